// Round 1
// baseline (100.442 us; speedup 1.0000x reference)
//
#include <hip/hip_runtime.h>

// Chamfer distance, B=4, N=M=8192, fp32 3D points.
// out[0 .. B*N)        = dist1 (min over xyz2 for each xyz1 point)
// out[B*N .. B*N+B*M)  = dist2 (min over xyz1 for each xyz2 point)

__global__ void chamfer_init_inf(float* __restrict__ out, int n) {
    int i = blockIdx.x * blockDim.x + threadIdx.x;
    int stride = gridDim.x * blockDim.x;
    for (; i < n; i += stride)
        out[i] = __uint_as_float(0x7F800000u);  // +inf
}

// One thread per query point; target dim split into gridDim.y segments.
// All lanes sweep the same target point -> wave-uniform loads (scalarizable).
__global__ __launch_bounds__(256) void chamfer_nn_min(
    const float* __restrict__ qry,   // [B, Nq, 3]
    const float* __restrict__ tgt,   // [B, Mt, 3]
    float* __restrict__ out,         // [B, Nq]
    int Nq, int Mt) {
    const int b   = blockIdx.z;
    const int seg = blockIdx.y;
    const int nseg = gridDim.y;
    const int q   = blockIdx.x * blockDim.x + threadIdx.x;

    const float* qp = qry + ((size_t)b * Nq + q) * 3;
    const float x = qp[0], y = qp[1], z = qp[2];

    const int seg_pts = Mt / nseg;               // divisible by construction
    const float* tbase = tgt + ((size_t)b * Mt + (size_t)seg * seg_pts) * 3;
    const float4* t4 = reinterpret_cast<const float4*>(tbase);  // 16B-aligned: seg_pts*3*4 % 16 == 0

    // 4 independent running minima to break the v_min dependence chain.
    float m0 = INFINITY, m1 = INFINITY, m2 = INFINITY, m3 = INFINITY;
    const int groups = seg_pts / 4;              // 4 points = 3 float4 loads
    #pragma unroll 4
    for (int g = 0; g < groups; ++g) {
        const float4 a = t4[3 * g + 0];
        const float4 bb = t4[3 * g + 1];
        const float4 c = t4[3 * g + 2];
        float dx, dy, dz, d;
        dx = x - a.x;  dy = y - a.y;  dz = z - a.z;
        d = dx * dx + dy * dy + dz * dz;  m0 = fminf(m0, d);
        dx = x - a.w;  dy = y - bb.x; dz = z - bb.y;
        d = dx * dx + dy * dy + dz * dz;  m1 = fminf(m1, d);
        dx = x - bb.z; dy = y - bb.w; dz = z - c.x;
        d = dx * dx + dy * dy + dz * dz;  m2 = fminf(m2, d);
        dx = x - c.y;  dy = y - c.z;  dz = z - c.w;
        d = dx * dx + dy * dy + dz * dz;  m3 = fminf(m3, d);
    }
    const float m = fminf(fminf(m0, m1), fminf(m2, m3));

    // Non-negative floats: uint bit-pattern order == float order.
    atomicMin(reinterpret_cast<unsigned int*>(out + (size_t)b * Nq + q),
              __float_as_uint(m));
}

extern "C" void kernel_launch(void* const* d_in, const int* in_sizes, int n_in,
                              void* d_out, int out_size, void* d_ws, size_t ws_size,
                              hipStream_t stream) {
    const float* xyz1 = (const float*)d_in[0];   // [B, N, 3]
    const float* xyz2 = (const float*)d_in[1];   // [B, M, 3]
    float* out = (float*)d_out;

    const int B = 4, N = 8192, M = 8192;
    const int S = 8;  // target-dim segments per query point

    // Re-init every call: harness poisons d_out and does not re-poison between replays.
    chamfer_init_inf<<<dim3(256), dim3(256), 0, stream>>>(out, out_size);

    // dist1: queries = xyz1, targets = xyz2
    dim3 grid1(N / 256, S, B);
    chamfer_nn_min<<<grid1, dim3(256), 0, stream>>>(xyz1, xyz2, out, N, M);

    // dist2: queries = xyz2, targets = xyz1
    dim3 grid2(M / 256, S, B);
    chamfer_nn_min<<<grid2, dim3(256), 0, stream>>>(xyz2, xyz1, out + (size_t)B * N, M, N);
}

// Round 2
// 75.789 us; speedup vs baseline: 1.3253x; 1.3253x over previous
//
#include <hip/hip_runtime.h>

// Chamfer distance, B=4, N=M=8192, fp32 3D points.
// out[0 .. B*N)        = dist1 (min over xyz2 for each xyz1 point)
// out[B*N .. 2*B*N)    = dist2 (min over xyz1 for each xyz2 point)
//
// Strategy: expansion form d = qsq + tsq - 2*q.t  (same formula as reference).
// Targets packed as float4(x,y,z,tsq) in d_ws by a prep kernel. Inner loop is
// 4 VALU ops/pair (3 fma + 1 min). Q=2 queries/thread, S=16 target segments,
// both directions in one launch -> 2048 blocks = 8 blocks/CU (full occupancy).
// Cross-segment combine via uint atomicMin (values clamped >= 0).

constexpr int Bc  = 4;
constexpr int Nc  = 8192;   // == M
constexpr int SEG = 16;     // target segments
constexpr int QPT = 2;      // queries per thread
constexpr int TPB = 256;

__global__ void init_out_inf(float* __restrict__ out, int n) {
    int i = blockIdx.x * blockDim.x + threadIdx.x;
    int stride = gridDim.x * blockDim.x;
    for (; i < n; i += stride)
        out[i] = __uint_as_float(0x7F800000u);  // +inf
}

__global__ void pack_pts(const float* __restrict__ src,   // [npts,3]
                         float4* __restrict__ dst,        // [npts]
                         int npts) {
    int i = blockIdx.x * blockDim.x + threadIdx.x;
    if (i < npts) {
        float x = src[3 * i + 0], y = src[3 * i + 1], z = src[3 * i + 2];
        dst[i] = make_float4(x, y, z, x * x + y * y + z * z);
    }
}

// blockIdx.z in [0, 2*B): dir = z>>2 (0: xyz1->xyz2, 1: xyz2->xyz1), b = z&3.
__global__ __launch_bounds__(TPB, 8) void chamfer_main(
    const float*  __restrict__ xyz1,   // [B,N,3]
    const float*  __restrict__ xyz2,   // [B,M,3]
    const float4* __restrict__ p1,     // [B,N] packed xyz1
    const float4* __restrict__ p2,     // [B,M] packed xyz2
    float* __restrict__ out) {
    const int z   = blockIdx.z;
    const int dir = z >> 2;
    const int b   = z & 3;
    const int seg = blockIdx.y;

    const float*  qry  = dir ? xyz2 : xyz1;
    const float4* tgt4 = dir ? p1 : p2;
    float* o = out + (size_t)dir * Bc * Nc + (size_t)b * Nc;

    const int q0 = blockIdx.x * (TPB * QPT) + threadIdx.x;  // thread's first query
    // Load QPT query points, precompute -2*coord and qsq.
    float m2x[QPT], m2y[QPT], m2z[QPT], qsq[QPT];
    #pragma unroll
    for (int j = 0; j < QPT; ++j) {
        const int q = q0 + j * TPB;
        const float* qp = qry + ((size_t)b * Nc + q) * 3;
        float x = qp[0], y = qp[1], zz = qp[2];
        m2x[j] = -2.0f * x; m2y[j] = -2.0f * y; m2z[j] = -2.0f * zz;
        qsq[j] = x * x + y * y + zz * zz;
    }

    constexpr int seg_pts = Nc / SEG;  // 512
    const float4* t = tgt4 + (size_t)b * Nc + (size_t)seg * seg_pts;

    // 2 accumulators per query (even/odd targets) for ILP.
    float mn0[QPT], mn1[QPT];
    #pragma unroll
    for (int j = 0; j < QPT; ++j) { mn0[j] = INFINITY; mn1[j] = INFINITY; }

    #pragma unroll 4
    for (int i = 0; i < seg_pts; i += 2) {
        const float4 t0 = t[i];
        const float4 t1 = t[i + 1];
        #pragma unroll
        for (int j = 0; j < QPT; ++j) {
            float d0 = fmaf(m2x[j], t0.x, fmaf(m2y[j], t0.y, fmaf(m2z[j], t0.z, t0.w)));
            mn0[j] = fminf(mn0[j], d0);
            float d1 = fmaf(m2x[j], t1.x, fmaf(m2y[j], t1.y, fmaf(m2z[j], t1.z, t1.w)));
            mn1[j] = fminf(mn1[j], d1);
        }
    }

    #pragma unroll
    for (int j = 0; j < QPT; ++j) {
        float d = qsq[j] + fminf(mn0[j], mn1[j]);
        d = fmaxf(d, 0.0f);  // keep uint atomicMin ordering valid
        atomicMin(reinterpret_cast<unsigned int*>(o + q0 + j * TPB),
                  __float_as_uint(d));
    }
}

// ---- Fallback (if d_ws is too small): direct formula, proven in round 1 ----
__global__ __launch_bounds__(256) void chamfer_nn_min_direct(
    const float* __restrict__ qry, const float* __restrict__ tgt,
    float* __restrict__ out, int Nq, int Mt) {
    const int b = blockIdx.z, seg = blockIdx.y, nseg = gridDim.y;
    const int q = blockIdx.x * blockDim.x + threadIdx.x;
    const float* qp = qry + ((size_t)b * Nq + q) * 3;
    const float x = qp[0], y = qp[1], z = qp[2];
    const int seg_pts = Mt / nseg;
    const float4* t4 = reinterpret_cast<const float4*>(
        tgt + ((size_t)b * Mt + (size_t)seg * seg_pts) * 3);
    float m0 = INFINITY, m1 = INFINITY, m2 = INFINITY, m3 = INFINITY;
    const int groups = seg_pts / 4;
    #pragma unroll 4
    for (int g = 0; g < groups; ++g) {
        const float4 a = t4[3 * g + 0], bb = t4[3 * g + 1], c = t4[3 * g + 2];
        float dx, dy, dz, d;
        dx = x - a.x;  dy = y - a.y;  dz = z - a.z;
        d = dx*dx + dy*dy + dz*dz;  m0 = fminf(m0, d);
        dx = x - a.w;  dy = y - bb.x; dz = z - bb.y;
        d = dx*dx + dy*dy + dz*dz;  m1 = fminf(m1, d);
        dx = x - bb.z; dy = y - bb.w; dz = z - c.x;
        d = dx*dx + dy*dy + dz*dz;  m2 = fminf(m2, d);
        dx = x - c.y;  dy = y - c.z;  dz = z - c.w;
        d = dx*dx + dy*dy + dz*dz;  m3 = fminf(m3, d);
    }
    const float m = fminf(fminf(m0, m1), fminf(m2, m3));
    atomicMin(reinterpret_cast<unsigned int*>(out + (size_t)b * Nq + q),
              __float_as_uint(m));
}

extern "C" void kernel_launch(void* const* d_in, const int* in_sizes, int n_in,
                              void* d_out, int out_size, void* d_ws, size_t ws_size,
                              hipStream_t stream) {
    const float* xyz1 = (const float*)d_in[0];   // [B, N, 3]
    const float* xyz2 = (const float*)d_in[1];   // [B, M, 3]
    float* out = (float*)d_out;

    const int npts = Bc * Nc;                    // per cloud: 32768 points
    const size_t need = 2 * (size_t)npts * sizeof(float4);  // 1 MiB

    init_out_inf<<<dim3(64), dim3(256), 0, stream>>>(out, out_size);

    if (ws_size >= need) {
        float4* p1 = (float4*)d_ws;
        float4* p2 = p1 + npts;
        pack_pts<<<dim3((npts + 255) / 256), dim3(256), 0, stream>>>(xyz1, p1, npts);
        pack_pts<<<dim3((npts + 255) / 256), dim3(256), 0, stream>>>(xyz2, p2, npts);

        dim3 grid(Nc / (TPB * QPT), SEG, 2 * Bc);  // 16 x 16 x 8 = 2048 blocks
        chamfer_main<<<grid, dim3(TPB), 0, stream>>>(xyz1, xyz2, p1, p2, out);
    } else {
        dim3 grid1(Nc / 256, SEG, Bc);
        chamfer_nn_min_direct<<<grid1, dim3(256), 0, stream>>>(xyz1, xyz2, out, Nc, Nc);
        chamfer_nn_min_direct<<<grid1, dim3(256), 0, stream>>>(xyz2, xyz1, out + (size_t)Bc * Nc, Nc, Nc);
    }
}

// Round 4
// 48.940 us; speedup vs baseline: 2.0523x; 1.5486x over previous
//
#include <hip/hip_runtime.h>

// Chamfer distance via MFMA, B=4, N=M=8192, fp32 3D points.
// d[n,m] = qsq[n] + tsq[m] - 2*q[n].t[m], computed ONCE per pair by
// v_mfma_f32_32x32x16_bf16 with split-precision bf16 operands (13 of 16 k-slots):
//   s0..s8 : per coord c: qh_c*(-2th_c), qh_c*(-2tl_c), ql_c*(-2th_c)
//   s9,s10 : qsq_h*1, qsq_l*1      s11,s12: 1*tsq_h, 1*tsq_l     s13..15: 0
// Slot-pairing note: pack_A and pack_B fill the SAME (lane-group, elem) slots
// with matching logical-k content; since A and B hardware layouts share the
// same k-pattern (mirror-symmetric), D = sum_s cA(s)*cB(s) holds regardless
// of the physical k mapping (contiguous or split halves).
// dist1 = row-min (running regs + lane butterfly), dist2 = col-min (per-tile
// reg min + shfl_xor(32) + LDS atomicMin, drained per block).

typedef short bf16x8 __attribute__((ext_vector_type(8)));   // 8 bf16 bit patterns
typedef float f32x16 __attribute__((ext_vector_type(16)));

constexpr int Bc  = 4;
constexpr int Nc  = 8192;
constexpr int NT  = Nc / 32;    // 256 tiles of 32 points
constexpr int SEG = 8;          // m-segments
constexpr int TPS = NT / SEG;   // 32 m-tiles per segment

__device__ inline unsigned short f2bf(float x) {
    unsigned u = __float_as_uint(x);
    unsigned r = (u + 0x7FFFu + ((u >> 16) & 1u)) >> 16;   // RNE
    return (unsigned short)r;
}
__device__ inline float bf2f(unsigned short h) {
    return __uint_as_float(((unsigned)h) << 16);
}
__device__ inline unsigned pack2(unsigned short lo, unsigned short hi) {
    return (unsigned)lo | ((unsigned)hi << 16);
}

__global__ void init_out_inf(float* __restrict__ out, int n) {
    int i = blockIdx.x * blockDim.x + threadIdx.x;
    int stride = gridDim.x * blockDim.x;
    for (; i < n; i += stride) out[i] = __uint_as_float(0x7F800000u);
}

// A fragments from xyz1. One thread per (b, tile, lane): writes 8 bf16 (16B).
__global__ void pack_A(const float* __restrict__ src, uint4* __restrict__ dst) {
    int tid  = blockIdx.x * 256 + threadIdx.x;     // [0, Bc*NT*64)
    int lane = tid & 63;
    int tile = (tid >> 6) & (NT - 1);
    int b    = tid >> 14;
    int row  = tile * 32 + (lane & 31);
    int kg   = lane >> 5;
    const float* p = src + ((size_t)b * Nc + row) * 3;
    float x = p[0], y = p[1], z = p[2];
    float qsq = x * x + y * y + z * z;
    unsigned short xh = f2bf(x), yh = f2bf(y), zh = f2bf(z);
    unsigned short xl = f2bf(x - bf2f(xh)), yl = f2bf(y - bf2f(yh)), zl = f2bf(z - bf2f(zh));
    unsigned short sh = f2bf(qsq), sl = f2bf(qsq - bf2f(sh));
    const unsigned short ONE = 0x3F80;
    uint4 v;
    if (kg == 0) {      // s0..s7: qh_x,qh_x,ql_x, qh_y,qh_y,ql_y, qh_z,qh_z
        v.x = pack2(xh, xh); v.y = pack2(xl, yh);
        v.z = pack2(yh, yl); v.w = pack2(zh, zh);
    } else {            // s8..s15: ql_z, qsq_h, qsq_l, 1, 1, 0,0,0
        v.x = pack2(zl, sh); v.y = pack2(sl, ONE);
        v.z = pack2(ONE, 0); v.w = 0;
    }
    dst[tid] = v;
}

// B fragments from xyz2 (same slot convention as pack_A).
__global__ void pack_B(const float* __restrict__ src, uint4* __restrict__ dst) {
    int tid  = blockIdx.x * 256 + threadIdx.x;
    int lane = tid & 63;
    int tile = (tid >> 6) & (NT - 1);
    int b    = tid >> 14;
    int col  = tile * 32 + (lane & 31);
    int kg   = lane >> 5;
    const float* p = src + ((size_t)b * Nc + col) * 3;
    float x = p[0], y = p[1], z = p[2];
    float tsq = x * x + y * y + z * z;
    unsigned short xh = f2bf(x), yh = f2bf(y), zh = f2bf(z);
    unsigned short m2xh = f2bf(-2.0f * bf2f(xh));
    unsigned short m2yh = f2bf(-2.0f * bf2f(yh));
    unsigned short m2zh = f2bf(-2.0f * bf2f(zh));
    unsigned short m2xl = f2bf(-2.0f * (x - bf2f(xh)));
    unsigned short m2yl = f2bf(-2.0f * (y - bf2f(yh)));
    unsigned short m2zl = f2bf(-2.0f * (z - bf2f(zh)));
    unsigned short sh = f2bf(tsq), sl = f2bf(tsq - bf2f(sh));
    const unsigned short ONE = 0x3F80;
    uint4 v;
    if (kg == 0) {      // s0..s7: -2th_x,-2tl_x,-2th_x, -2th_y,-2tl_y,-2th_y, -2th_z,-2tl_z
        v.x = pack2(m2xh, m2xl); v.y = pack2(m2xh, m2yh);
        v.z = pack2(m2yl, m2yh); v.w = pack2(m2zh, m2zl);
    } else {            // s8..s15: -2th_z, 1, 1, tsq_h, tsq_l, 0,0,0
        v.x = pack2(m2zh, ONE);  v.y = pack2(ONE, sh);
        v.z = pack2(sl, 0);      v.w = 0;
    }
    dst[tid] = v;
}

// Main: grid (NT/4, SEG, Bc), 256 threads = 4 waves. Wave w owns query strip
// n_tile = bx*4+w (32 rows), sweeps TPS m-tiles of segment `seg`.
__global__ __launch_bounds__(256, 4) void chamfer_mfma(
    const uint4* __restrict__ afrag,   // [Bc*NT*64]
    const uint4* __restrict__ bfrag,   // [Bc*NT*64]
    float* __restrict__ out) {
    __shared__ unsigned sMin[TPS * 32];            // col-min partials (4KB)
    const int tid = threadIdx.x, lane = tid & 63, wave = tid >> 6;
    const int b = blockIdx.z, seg = blockIdx.y;
    const int n_tile = blockIdx.x * 4 + wave;

    for (int i = tid; i < TPS * 32; i += 256) sMin[i] = 0x7F800000u;
    __syncthreads();

    const bf16x8 av = __builtin_bit_cast(bf16x8,
        afrag[((size_t)(b * NT + n_tile)) * 64 + lane]);
    f32x16 zc{};                                    // zero C fragment
    float rmin[16];
    #pragma unroll
    for (int r = 0; r < 16; ++r) rmin[r] = INFINITY;

    const uint4* bp = bfrag + ((size_t)(b * NT + seg * TPS)) * 64 + lane;
    #pragma unroll 2
    for (int mt = 0; mt < TPS; ++mt) {
        const bf16x8 bv = __builtin_bit_cast(bf16x8, bp[(size_t)mt * 64]);
        const f32x16 d = __builtin_amdgcn_mfma_f32_32x32x16_bf16(av, bv, zc, 0, 0, 0);
        // dist2: min over the 16 rows this lane holds, then across lane-halves.
        float t0 = fminf(fminf(d[0], d[1]),  fminf(d[2], d[3]));
        float t1 = fminf(fminf(d[4], d[5]),  fminf(d[6], d[7]));
        float t2 = fminf(fminf(d[8], d[9]),  fminf(d[10], d[11]));
        float t3 = fminf(fminf(d[12], d[13]), fminf(d[14], d[15]));
        float t = fminf(fminf(t0, t1), fminf(t2, t3));
        t = fminf(t, __shfl_xor(t, 32));
        t = fmaxf(t, 0.0f);
        if (lane < 32)
            atomicMin(&sMin[mt * 32 + lane], __float_as_uint(t));
        // dist1: running row-min.
        #pragma unroll
        for (int r = 0; r < 16; ++r) rmin[r] = fminf(rmin[r], d[r]);
    }

    // dist1: butterfly over the 32 columns (lane bits 0..4; bit 5 = row group).
    #pragma unroll
    for (int m = 1; m <= 16; m <<= 1) {
        #pragma unroll
        for (int r = 0; r < 16; ++r)
            rmin[r] = fminf(rmin[r], __shfl_xor(rmin[r], m));
    }
    if ((lane & 31) == 0) {
        unsigned* d1 = (unsigned*)out + (size_t)b * Nc + n_tile * 32;
        const int hi = lane >> 5;
        #pragma unroll
        for (int r = 0; r < 16; ++r) {
            int row = (r & 3) + 8 * (r >> 2) + 4 * hi;
            atomicMin(&d1[row], __float_as_uint(fmaxf(rmin[r], 0.0f)));
        }
    }

    __syncthreads();
    unsigned* d2 = (unsigned*)out + (size_t)Bc * Nc + (size_t)b * Nc + seg * (TPS * 32);
    for (int i = tid; i < TPS * 32; i += 256)
        atomicMin(&d2[i], sMin[i]);
}

// ---- Fallback (ws too small): round-2 expansion kernel ----
constexpr int QPT = 2, TPB = 256;
__global__ void pack_pts(const float* __restrict__ src, float4* __restrict__ dst, int npts) {
    int i = blockIdx.x * blockDim.x + threadIdx.x;
    if (i < npts) {
        float x = src[3 * i], y = src[3 * i + 1], z = src[3 * i + 2];
        dst[i] = make_float4(x, y, z, x * x + y * y + z * z);
    }
}
__global__ __launch_bounds__(TPB, 8) void chamfer_fb(
    const float* __restrict__ xyz1, const float* __restrict__ xyz2,
    const float4* __restrict__ p1, const float4* __restrict__ p2,
    float* __restrict__ out) {
    const int z = blockIdx.z, dir = z >> 2, b = z & 3, seg = blockIdx.y;
    const float*  qry  = dir ? xyz2 : xyz1;
    const float4* tgt4 = dir ? p1 : p2;
    float* o = out + (size_t)dir * Bc * Nc + (size_t)b * Nc;
    const int q0 = blockIdx.x * (TPB * QPT) + threadIdx.x;
    float m2x[QPT], m2y[QPT], m2z[QPT], qsq[QPT];
    #pragma unroll
    for (int j = 0; j < QPT; ++j) {
        const float* qp = qry + ((size_t)b * Nc + q0 + j * TPB) * 3;
        float x = qp[0], y = qp[1], zz = qp[2];
        m2x[j] = -2.f * x; m2y[j] = -2.f * y; m2z[j] = -2.f * zz;
        qsq[j] = x * x + y * y + zz * zz;
    }
    constexpr int seg_pts = Nc / 16;
    const float4* t = tgt4 + (size_t)b * Nc + (size_t)seg * seg_pts;
    float mn0[QPT], mn1[QPT];
    #pragma unroll
    for (int j = 0; j < QPT; ++j) { mn0[j] = INFINITY; mn1[j] = INFINITY; }
    #pragma unroll 4
    for (int i = 0; i < seg_pts; i += 2) {
        const float4 t0 = t[i], t1 = t[i + 1];
        #pragma unroll
        for (int j = 0; j < QPT; ++j) {
            mn0[j] = fminf(mn0[j], fmaf(m2x[j], t0.x, fmaf(m2y[j], t0.y, fmaf(m2z[j], t0.z, t0.w))));
            mn1[j] = fminf(mn1[j], fmaf(m2x[j], t1.x, fmaf(m2y[j], t1.y, fmaf(m2z[j], t1.z, t1.w))));
        }
    }
    #pragma unroll
    for (int j = 0; j < QPT; ++j) {
        float d = fmaxf(qsq[j] + fminf(mn0[j], mn1[j]), 0.f);
        atomicMin((unsigned*)(o + q0 + j * TPB), __float_as_uint(d));
    }
}

extern "C" void kernel_launch(void* const* d_in, const int* in_sizes, int n_in,
                              void* d_out, int out_size, void* d_ws, size_t ws_size,
                              hipStream_t stream) {
    const float* xyz1 = (const float*)d_in[0];
    const float* xyz2 = (const float*)d_in[1];
    float* out = (float*)d_out;

    const int nfrag = Bc * NT * 64;                       // 65536 uint4 per array
    const size_t need = 2 * (size_t)nfrag * sizeof(uint4); // 2 MiB

    init_out_inf<<<dim3(64), dim3(256), 0, stream>>>(out, out_size);

    if (ws_size >= need) {
        uint4* afrag = (uint4*)d_ws;
        uint4* bfrag = afrag + nfrag;
        pack_A<<<dim3(nfrag / 256), dim3(256), 0, stream>>>(xyz1, afrag);
        pack_B<<<dim3(nfrag / 256), dim3(256), 0, stream>>>(xyz2, bfrag);
        dim3 grid(NT / 4, SEG, Bc);                       // 64 x 8 x 4 = 2048 blocks
        chamfer_mfma<<<grid, dim3(256), 0, stream>>>(afrag, bfrag, out);
    } else if (ws_size >= 2 * (size_t)Bc * Nc * sizeof(float4)) {
        float4* p1 = (float4*)d_ws;
        float4* p2 = p1 + Bc * Nc;
        pack_pts<<<dim3(Bc * Nc / 256), dim3(256), 0, stream>>>(xyz1, p1, Bc * Nc);
        pack_pts<<<dim3(Bc * Nc / 256), dim3(256), 0, stream>>>(xyz2, p2, Bc * Nc);
        dim3 grid(Nc / (TPB * QPT), 16, 2 * Bc);
        chamfer_fb<<<grid, dim3(TPB), 0, stream>>>(xyz1, xyz2, p1, p2, out);
    }
}

// Round 5
// 45.020 us; speedup vs baseline: 2.2311x; 1.0871x over previous
//
#include <hip/hip_runtime.h>

// Chamfer distance via MFMA, B=4, N=M=8192, fp32 3D points.
// d[n,m] = qsq[n] + tsq[m] - 2*q[n].t[m] via v_mfma_f32_32x32x16_bf16 with
// split-precision bf16 operands (13 of 16 k-slots):
//   s0..s8 : per coord c: qh_c*(-2th_c), qh_c*(-2tl_c), ql_c*(-2th_c)
//   s9,s10 : qsq_h*1, qsq_l*1   s11,s12: 1*tsq_h, 1*tsq_l   s13..15: 0
// TWO passes (one per direction, merged in one launch via blockIdx.z): each
// pass computes only the running ROW-min (16 independent fmin per MFMA) —
// no per-iteration tree/shfl/atomic (round-4's stall source). Epilogue:
// padded-LDS transpose + 1 global atomicMin per output row.

typedef short bf16x8 __attribute__((ext_vector_type(8)));
typedef float f32x16 __attribute__((ext_vector_type(16)));

constexpr int Bc  = 4;
constexpr int Nc  = 8192;
constexpr int NT  = Nc / 32;    // 256 tiles of 32 points
constexpr int SEG = 8;          // target segments (parallelism across m)
constexpr int TPS = NT / SEG;   // 32 m-tiles per segment

__device__ inline unsigned short f2bf(float x) {
    unsigned u = __float_as_uint(x);
    unsigned r = (u + 0x7FFFu + ((u >> 16) & 1u)) >> 16;   // RNE
    return (unsigned short)r;
}
__device__ inline float bf2f(unsigned short h) {
    return __uint_as_float(((unsigned)h) << 16);
}
__device__ inline unsigned pack2(unsigned short lo, unsigned short hi) {
    return (unsigned)lo | ((unsigned)hi << 16);
}

__global__ void init_out_inf(float* __restrict__ out, int n) {
    int i = blockIdx.x * blockDim.x + threadIdx.x;
    int stride = gridDim.x * blockDim.x;
    for (; i < n; i += stride) out[i] = __uint_as_float(0x7F800000u);
}

// One launch packs BOTH clouds into q-form and t-form fragment arrays.
// qf/tf: [2 clouds][Bc*NT*64] uint4. blockIdx.y = cloud.
__global__ void pack_both(const float* __restrict__ xyz1,
                          const float* __restrict__ xyz2,
                          uint4* __restrict__ qf, uint4* __restrict__ tf) {
    const int tid   = blockIdx.x * 256 + threadIdx.x;   // [0, Bc*NT*64)
    const int cloud = blockIdx.y;
    const float* src = cloud ? xyz2 : xyz1;
    const int lane = tid & 63;
    const int tile = (tid >> 6) & (NT - 1);
    const int b    = tid >> 14;
    const int pt   = tile * 32 + (lane & 31);
    const int kg   = lane >> 5;
    const float* p = src + ((size_t)b * Nc + pt) * 3;
    float x = p[0], y = p[1], z = p[2];
    float sq = x * x + y * y + z * z;
    unsigned short xh = f2bf(x), yh = f2bf(y), zh = f2bf(z);
    unsigned short xl = f2bf(x - bf2f(xh)), yl = f2bf(y - bf2f(yh)), zl = f2bf(z - bf2f(zh));
    unsigned short sh = f2bf(sq), sl = f2bf(sq - bf2f(sh));
    unsigned short m2xh = f2bf(-2.0f * bf2f(xh));
    unsigned short m2yh = f2bf(-2.0f * bf2f(yh));
    unsigned short m2zh = f2bf(-2.0f * bf2f(zh));
    unsigned short m2xl = f2bf(-2.0f * (x - bf2f(xh)));
    unsigned short m2yl = f2bf(-2.0f * (y - bf2f(yh)));
    unsigned short m2zl = f2bf(-2.0f * (z - bf2f(zh)));
    const unsigned short ONE = 0x3F80;
    uint4 q, t;
    if (kg == 0) {
        // q slots s0..s7: qh_x,qh_x,ql_x, qh_y,qh_y,ql_y, qh_z,qh_z
        q.x = pack2(xh, xh); q.y = pack2(xl, yh);
        q.z = pack2(yh, yl); q.w = pack2(zh, zh);
        // t slots s0..s7: -2th_x,-2tl_x,-2th_x, -2th_y,-2tl_y,-2th_y, -2th_z,-2tl_z
        t.x = pack2(m2xh, m2xl); t.y = pack2(m2xh, m2yh);
        t.z = pack2(m2yl, m2yh); t.w = pack2(m2zh, m2zl);
    } else {
        // q slots s8..s15: ql_z, qsq_h, qsq_l, 1, 1, 0,0,0
        q.x = pack2(zl, sh); q.y = pack2(sl, ONE);
        q.z = pack2(ONE, 0); q.w = 0;
        // t slots s8..s15: -2th_z, 1, 1, tsq_h, tsq_l, 0,0,0
        t.x = pack2(m2zh, ONE); t.y = pack2(ONE, sh);
        t.z = pack2(sl, 0);     t.w = 0;
    }
    const size_t FR = (size_t)Bc * NT * 64;
    qf[(size_t)cloud * FR + tid] = q;
    tf[(size_t)cloud * FR + tid] = t;
}

// Main: grid (NT/4, SEG, 2*Bc), 256 threads = 4 waves.
// blockIdx.z: dir = z>>2 (0: xyz1->xyz2, 1: xyz2->xyz1), b = z&3.
// Wave w owns query tile n_tile = bx*4+w (32 rows of direction-dir queries),
// sweeps TPS target tiles of segment `seg` with a pure running row-min.
__global__ __launch_bounds__(256) void chamfer_dir(
    const uint4* __restrict__ qf,   // [2][Bc*NT*64]
    const uint4* __restrict__ tf,   // [2][Bc*NT*64]
    float* __restrict__ out) {
    __shared__ float sRed[4][32][33];              // padded: conflict-free transpose
    const int tid = threadIdx.x, lane = tid & 63, wave = tid >> 6;
    const int z = blockIdx.z, dir = z >> 2, b = z & 3, seg = blockIdx.y;
    const int qc = dir, tc = dir ^ 1;              // query cloud / target cloud
    const size_t FR = (size_t)Bc * NT * 64;

    const int n_tile = blockIdx.x * 4 + wave;
    const bf16x8 av = __builtin_bit_cast(bf16x8,
        qf[(size_t)qc * FR + ((size_t)(b * NT + n_tile)) * 64 + lane]);
    f32x16 zc{};
    float rmin[16];
    #pragma unroll
    for (int r = 0; r < 16; ++r) rmin[r] = INFINITY;

    const uint4* bp = tf + (size_t)tc * FR + ((size_t)(b * NT + seg * TPS)) * 64 + lane;
    #pragma unroll 4
    for (int mt = 0; mt < TPS; ++mt) {
        const bf16x8 bv = __builtin_bit_cast(bf16x8, bp[(size_t)mt * 64]);
        const f32x16 d = __builtin_amdgcn_mfma_f32_32x32x16_bf16(av, bv, zc, 0, 0, 0);
        #pragma unroll
        for (int r = 0; r < 16; ++r) rmin[r] = fminf(rmin[r], d[r]);
    }

    // Epilogue: transpose through padded LDS, then reduce each row's 32 cols.
    const int col = lane & 31, hi = lane >> 5;
    #pragma unroll
    for (int r = 0; r < 16; ++r) {
        const int row = (r & 3) + 8 * (r >> 2) + 4 * hi;   // C/D layout (m74/m101)
        sRed[wave][row][col] = rmin[r];
    }
    __syncthreads();

    // 256 threads / 128 rows: 2 threads per row, 16 values each.
    const int row2 = tid >> 1, half = tid & 1;
    const int w = row2 >> 5, rr = row2 & 31;
    const float* rp = &sRed[w][rr][half * 16];
    float v0 = fminf(fminf(rp[0], rp[1]),  fminf(rp[2], rp[3]));
    float v1 = fminf(fminf(rp[4], rp[5]),  fminf(rp[6], rp[7]));
    float v2 = fminf(fminf(rp[8], rp[9]),  fminf(rp[10], rp[11]));
    float v3 = fminf(fminf(rp[12], rp[13]), fminf(rp[14], rp[15]));
    float v = fminf(fminf(v0, v1), fminf(v2, v3));
    v = fminf(v, __shfl_xor(v, 1));
    if (!half) {
        const int n = (blockIdx.x * 4 + w) * 32 + rr;
        unsigned* o = (unsigned*)out + (size_t)dir * Bc * Nc + (size_t)b * Nc + n;
        atomicMin(o, __float_as_uint(fmaxf(v, 0.0f)));  // clamp: uint order valid
    }
}

// ---- Fallback (ws too small): round-2 expansion kernel ----
constexpr int QPT = 2, TPB = 256;
__global__ void pack_pts(const float* __restrict__ src, float4* __restrict__ dst, int npts) {
    int i = blockIdx.x * blockDim.x + threadIdx.x;
    if (i < npts) {
        float x = src[3 * i], y = src[3 * i + 1], z = src[3 * i + 2];
        dst[i] = make_float4(x, y, z, x * x + y * y + z * z);
    }
}
__global__ __launch_bounds__(TPB, 8) void chamfer_fb(
    const float* __restrict__ xyz1, const float* __restrict__ xyz2,
    const float4* __restrict__ p1, const float4* __restrict__ p2,
    float* __restrict__ out) {
    const int z = blockIdx.z, dir = z >> 2, b = z & 3, seg = blockIdx.y;
    const float*  qry  = dir ? xyz2 : xyz1;
    const float4* tgt4 = dir ? p1 : p2;
    float* o = out + (size_t)dir * Bc * Nc + (size_t)b * Nc;
    const int q0 = blockIdx.x * (TPB * QPT) + threadIdx.x;
    float m2x[QPT], m2y[QPT], m2z[QPT], qsq[QPT];
    #pragma unroll
    for (int j = 0; j < QPT; ++j) {
        const float* qp = qry + ((size_t)b * Nc + q0 + j * TPB) * 3;
        float x = qp[0], y = qp[1], zz = qp[2];
        m2x[j] = -2.f * x; m2y[j] = -2.f * y; m2z[j] = -2.f * zz;
        qsq[j] = x * x + y * y + zz * zz;
    }
    constexpr int seg_pts = Nc / 16;
    const float4* t = tgt4 + (size_t)b * Nc + (size_t)seg * seg_pts;
    float mn0[QPT], mn1[QPT];
    #pragma unroll
    for (int j = 0; j < QPT; ++j) { mn0[j] = INFINITY; mn1[j] = INFINITY; }
    #pragma unroll 4
    for (int i = 0; i < seg_pts; i += 2) {
        const float4 t0 = t[i], t1 = t[i + 1];
        #pragma unroll
        for (int j = 0; j < QPT; ++j) {
            mn0[j] = fminf(mn0[j], fmaf(m2x[j], t0.x, fmaf(m2y[j], t0.y, fmaf(m2z[j], t0.z, t0.w))));
            mn1[j] = fminf(mn1[j], fmaf(m2x[j], t1.x, fmaf(m2y[j], t1.y, fmaf(m2z[j], t1.z, t1.w))));
        }
    }
    #pragma unroll
    for (int j = 0; j < QPT; ++j) {
        float d = fmaxf(qsq[j] + fminf(mn0[j], mn1[j]), 0.f);
        atomicMin((unsigned*)(o + q0 + j * TPB), __float_as_uint(d));
    }
}

extern "C" void kernel_launch(void* const* d_in, const int* in_sizes, int n_in,
                              void* d_out, int out_size, void* d_ws, size_t ws_size,
                              hipStream_t stream) {
    const float* xyz1 = (const float*)d_in[0];
    const float* xyz2 = (const float*)d_in[1];
    float* out = (float*)d_out;

    const size_t FR = (size_t)Bc * NT * 64;               // 65536 uint4 per array
    const size_t need = 4 * FR * sizeof(uint4);           // 4 MiB (qf[2] + tf[2])

    init_out_inf<<<dim3(64), dim3(256), 0, stream>>>(out, out_size);

    if (ws_size >= need) {
        uint4* qf = (uint4*)d_ws;          // [2][FR]
        uint4* tf = qf + 2 * FR;           // [2][FR]
        pack_both<<<dim3(FR / 256, 2), dim3(256), 0, stream>>>(xyz1, xyz2, qf, tf);
        dim3 grid(NT / 4, SEG, 2 * Bc);                   // 64 x 8 x 8 = 4096 blocks
        chamfer_dir<<<grid, dim3(256), 0, stream>>>(qf, tf, out);
    } else if (ws_size >= 2 * (size_t)Bc * Nc * sizeof(float4)) {
        float4* p1 = (float4*)d_ws;
        float4* p2 = p1 + Bc * Nc;
        pack_pts<<<dim3(Bc * Nc / 256), dim3(256), 0, stream>>>(xyz1, p1, Bc * Nc);
        pack_pts<<<dim3(Bc * Nc / 256), dim3(256), 0, stream>>>(xyz2, p2, Bc * Nc);
        dim3 grid(Nc / (TPB * QPT), 16, 2 * Bc);
        chamfer_fb<<<grid, dim3(TPB), 0, stream>>>(xyz1, xyz2, p1, p2, out);
    }
}